// Round 8
// baseline (131.164 us; speedup 1.0000x reference)
//
#include <hip/hip_runtime.h>
#include <hip/hip_bf16.h>

// Problem constants (EdgeAwareMultiHeadAttention)
constexpr int Bb   = 4;
constexpr int Nn   = 256;
constexpr int HID  = 256;
constexpr int Ee   = 64;
constexpr int Hh   = 4;
constexpr int OUTc = 128;   // HID/2
constexpr int Dd   = 32;    // OUT/H
constexpr int AGG  = 260;   // H*(2D+1)
constexpr int QA_LD = 264;  // bf16 row stride for Q-proj A tile

// ws layout (float offsets)
constexpr size_t WS_WRT   = 0;                                 // 260*128
constexpr size_t WS_FRAGV = WS_WRT + (size_t)AGG * OUTc;       // 1024 entries = 4096 floats
constexpr size_t WS_FRAGQ = WS_FRAGV + 4096;                   // (unused)
constexpr size_t WS_UFRAG = WS_FRAGQ + 16384;

typedef __attribute__((ext_vector_type(8))) short short8;
typedef __attribute__((ext_vector_type(4))) float floatx4;

// HW packed f32x2 -> bf16x2 (v_cvt_pk_bf16_f32, RNE)
__device__ __forceinline__ unsigned pk2(float a, float b) {
    union { __hip_bfloat162 h; unsigned u; } cv;
    cv.h = __float22bfloat162_rn(float2{a, b});
    return cv.u;
}

__device__ __forceinline__ short8 pack8(floatx4 f0, floatx4 f1) {
    union { short8 s; unsigned u[4]; } r;
    r.u[0] = pk2(f0[0], f0[1]);
    r.u[1] = pk2(f0[2], f0[3]);
    r.u[2] = pk2(f1[0], f1[1]);
    r.u[3] = pk2(f1[2], f1[3]);
    return r.s;
}

// async global->LDS, 16B per lane. dst must be wave-uniform (HW adds lane*16).
__device__ __forceinline__ void gload16(const float* g, float* l) {
    __builtin_amdgcn_global_load_lds(
        (const __attribute__((address_space(1))) void*)g,
        (__attribute__((address_space(3))) void*)l, 16, 0, 0);
}

// ---------------- K_prep: weight prepack (W_V frags, W_RT) + q/u projection ----------------
// (identical to R7 — passed with absmax 0.0625)
__global__ __launch_bounds__(256)
void eama_prep(const float* __restrict__ W_Q, const float* __restrict__ W_V,
               const float* __restrict__ W_R, const float* __restrict__ h_x,
               const float* __restrict__ W_K,
               unsigned short* __restrict__ wfragV, float* __restrict__ W_RT,
               unsigned short* __restrict__ ufrag)
{
    __shared__ __align__(16) unsigned short sA[16 * QA_LD];
    __shared__ __align__(16) float sqL[16][132];
    __shared__ __align__(16) float sU2[16][256];

    const int tid = threadIdx.x;
    const int bid = blockIdx.x;

    if (bid < 4) {
        const int e    = bid * 256 + tid;          // 0..1023
        const int lane = e & 63;
        const int ks   = (e >> 6) & 1;
        const int ct   = e >> 7;                   // 0..7
        const int ncol = lane & 15, q8 = lane >> 4;
        const float* row = W_V + (ct * 16 + ncol) * Ee;
        const int k0 = ks * 32 + q8 * 8;
        floatx4 f0 = *(const floatx4*)(row + k0);
        floatx4 f1 = *(const floatx4*)(row + k0 + 4);
        *(short8*)(wfragV + (size_t)e * 8) = pack8(f0, f1);
        return;
    }
    if (bid < 134) {
        const int i = (bid - 4) * 256 + tid;       // 0..33279
        if (i < AGG * OUTc) {
            const int c = i & 127, j = i >> 7;
            W_RT[j * OUTc + c] = W_R[c * AGG + j];
        }
        return;
    }

    // ---- q = h_x @ W_Q^T (MFMA), then u[h,e] = q.W_K * rsqrt(D)*log2e -> ufrag ----
    const int b0   = (bid - 134) * 16;
    const int lane = tid & 63;
    const int wv   = tid >> 6;
    const int ncol = lane & 15, q8 = lane >> 4;

    short8 bq[2][8];
    #pragma unroll
    for (int ct = 0; ct < 2; ++ct)
        #pragma unroll
        for (int ks = 0; ks < 8; ++ks) {
            const float* row = W_Q + (size_t)(wv * 32 + ct * 16 + ncol) * HID + ks * 32 + q8 * 8;
            bq[ct][ks] = pack8(*(const floatx4*)row, *(const floatx4*)(row + 4));
        }
    #pragma unroll
    for (int i = 0; i < 2; ++i) {
        const int idx = tid + i * 256;
        const int r = idx >> 5, blk = idx & 31;
        const float* src = h_x + (size_t)(b0 + r) * HID + blk * 8;
        floatx4 f0 = *(const floatx4*)(src);
        floatx4 f1 = *(const floatx4*)(src + 4);
        *(short8*)&sA[r * QA_LD + blk * 8] = pack8(f0, f1);
    }
    __syncthreads();
    floatx4 acc[2] = {(floatx4){0,0,0,0}, (floatx4){0,0,0,0}};
    #pragma unroll
    for (int ks = 0; ks < 8; ++ks) {
        short8 a = *(const short8*)&sA[ncol * QA_LD + ks * 32 + q8 * 8];
        acc[0] = __builtin_amdgcn_mfma_f32_16x16x32_bf16(a, bq[0][ks], acc[0], 0, 0, 0);
        acc[1] = __builtin_amdgcn_mfma_f32_16x16x32_bf16(a, bq[1][ks], acc[1], 0, 0, 0);
    }
    #pragma unroll
    for (int ct = 0; ct < 2; ++ct)
        #pragma unroll
        for (int rr = 0; rr < 4; ++rr)
            sqL[q8 * 4 + rr][wv * 32 + ct * 16 + ncol] = acc[ct][rr];
    __syncthreads();

    {
        const int h = wv, e = lane;
        float a16[16];
        #pragma unroll
        for (int i = 0; i < 16; ++i) a16[i] = 0.f;
        #pragma unroll
        for (int d4 = 0; d4 < 8; ++d4) {
            float wk0 = W_K[(h * Dd + d4 * 4 + 0) * Ee + e];
            float wk1 = W_K[(h * Dd + d4 * 4 + 1) * Ee + e];
            float wk2 = W_K[(h * Dd + d4 * 4 + 2) * Ee + e];
            float wk3 = W_K[(h * Dd + d4 * 4 + 3) * Ee + e];
            #pragma unroll
            for (int b16 = 0; b16 < 16; ++b16) {
                floatx4 qv = *(const floatx4*)&sqL[b16][h * Dd + d4 * 4];
                a16[b16] += (qv[0] * wk0 + qv[1] * wk1) + (qv[2] * wk2 + qv[3] * wk3);
            }
        }
        // rsqrt(D) * log2(e): scores leave MFMA already in log2 domain
        #pragma unroll
        for (int b16 = 0; b16 < 16; ++b16)
            sU2[b16][h * 64 + e] = a16[b16] * (0.1767766952966369f * 1.4426950408889634f);
    }
    __syncthreads();

    #pragma unroll
    for (int k = 0; k < 8; ++k) {
        const int ei   = tid + k * 256;
        const int b16  = ei >> 7;
        const int rest = ei & 127;
        const int ks   = rest >> 6;
        const int l    = rest & 63;
        const int nc   = l & 15, qq = l >> 4;
        short8 v = {0, 0, 0, 0, 0, 0, 0, 0};
        if (nc < Hh) {
            floatx4 f0 = *(const floatx4*)&sU2[b16][nc * 64 + ks * 32 + qq * 8];
            floatx4 f1 = *(const floatx4*)&sU2[b16][nc * 64 + ks * 32 + qq * 8 + 4];
            v = pack8(f0, f1);
        }
        *(short8*)(ufrag + ((size_t)((b0 + b16) * 2 + ks) * 64 + l) * 8) = v;
    }
}

// ---------------- K_full: one block per bn — 8 WAVES, serial depth halved ----------------
// Depth experiment: every prior variant gave each wave 4 serial tile-phases; wall
// tracked phase count across 8 data points (R3/R5 fused = more phases = 56us;
// R2/R6/R7 = 4 phases = ~38us) while BW/latency/request-rate/VALU cuts were all
// null. Here: 512 threads, wave w owns rows (w*2+it)*16..+16, it in {0,1} — TWO
// phases, both tiles staged upfront (vmcnt 4 -> 0). Math is partition-invariant
// (vs/vm/asum are pure reductions over m-rows). LDS 67.6KB -> 2 blocks/CU,
// 16 waves/CU unchanged. Epilogue reduces 8 wave-partials; GEMV = 4 parts x 65 j.
__global__ __launch_bounds__(512, 2)
void eama_full(const float* __restrict__ h_e, const float* __restrict__ h_m,
               const unsigned short* __restrict__ wfragV,
               const unsigned short* __restrict__ ufrag,
               const float* __restrict__ W_RT, float* __restrict__ out)
{
    // 64KB staging: [wave][tile][chunk j][slot][4 floats]. Dead after the main
    // loop; reused for the epilogue (per-wave region = own 2048 floats).
    __shared__ __align__(16) float sStage[8][2][4][64][4];
    __shared__ __align__(16) float sS[8][16][4];   // per-wave score patch

    const int tid  = threadIdx.x;
    const int lane = tid & 63;
    const int w    = tid >> 6;            // 0..7
    const int ncol = lane & 15;
    const int q8   = lane >> 4;
    const int bn   = blockIdx.x;
    const float maskv = h_m[bn];

    // B fragments once per wave (coalesced 16B/lane, L2-resident)
    short8 bfV[8][2];
    #pragma unroll
    for (int ct = 0; ct < 8; ++ct)
        #pragma unroll
        for (int ks = 0; ks < 2; ++ks)
            bfV[ct][ks] = *(const short8*)(wfragV + ((size_t)(ct * 2 + ks) * 64 + lane) * 8);
    short8 bu0 = *(const short8*)(ufrag + ((size_t)(bn * 2 + 0) * 64 + lane) * 8);
    short8 bu1 = *(const short8*)(ufrag + ((size_t)(bn * 2 + 1) * 64 + lane) * 8);
    asm volatile("" ::: "memory");   // pin B-frag loads before the staging stream (vmcnt order)

    const float* heb = h_e + (size_t)bn * Nn * Ee;

    // staging per-lane source offset (R7 permutation): lane l fetches piece
    // (rl = l>>4, t = ((l&15)-5*rl)&15) -> linear dst slot l = rl*16+((t+5rl)&15).
    const int rl_s = lane >> 4;
    const int t_s  = ((lane & 15) - 5 * rl_s) & 15;
    const int soff = rl_s * 64 + t_s * 4;   // float offset within the chunk's 1KB

    // consumer word offsets (within a chunk) for row ncol: chunk jc = ncol>>2, rl = ncol&3
    const int rl_c = ncol & 3;
    const int jc   = ncol >> 2;
    const int o0 = (rl_c * 16 + (((q8 * 2)     + 5 * rl_c) & 15)) * 4;
    const int o1 = (rl_c * 16 + (((q8 * 2 + 1) + 5 * rl_c) & 15)) * 4;
    const int o2 = (rl_c * 16 + (((q8 * 2 + 8) + 5 * rl_c) & 15)) * 4;
    const int o3 = (rl_c * 16 + (((q8 * 2 + 9) + 5 * rl_c) & 15)) * 4;

    // tile it (global rows (w*2+it)*16..+16): 4 async contiguous-1KB copies
    #define STAGE(it_) do { \
        const float* ar_ = heb + (size_t)((w * 2 + (it_)) * 16) * Ee + soff; \
        gload16(ar_,       &sStage[w][it_][0][0][0]); \
        gload16(ar_ + 256, &sStage[w][it_][1][0][0]); \
        gload16(ar_ + 512, &sStage[w][it_][2][0][0]); \
        gload16(ar_ + 768, &sStage[w][it_][3][0][0]); \
    } while (0)

    STAGE(0);
    STAGE(1);

    float vs[8], vm[8], asumH = 0.f;
    #pragma unroll
    for (int ct = 0; ct < 8; ++ct) { vs[ct] = 0.f; vm[ct] = -3.402823466e38f; }

    #pragma unroll
    for (int it = 0; it < 2; ++it) {
        if (it == 0) asm volatile("s_waitcnt vmcnt(4)" ::: "memory");
        else         asm volatile("s_waitcnt vmcnt(0)" ::: "memory");

        const float* chunkp = &sStage[w][it][jc][0][0];
        floatx4 c0 = *(const floatx4*)(chunkp + o0);
        floatx4 c1 = *(const floatx4*)(chunkp + o1);
        floatx4 c2 = *(const floatx4*)(chunkp + o2);
        floatx4 c3 = *(const floatx4*)(chunkp + o3);
        short8 af0 = pack8(c0, c1);
        short8 af1 = pack8(c2, c3);

        floatx4 accV[8], accS = (floatx4){0, 0, 0, 0};
        #pragma unroll
        for (int ct = 0; ct < 8; ++ct) accV[ct] = (floatx4){0, 0, 0, 0};
        __builtin_amdgcn_s_setprio(1);
        #pragma unroll
        for (int ct = 0; ct < 8; ++ct) {
            accV[ct] = __builtin_amdgcn_mfma_f32_16x16x32_bf16(af0, bfV[ct][0], accV[ct], 0, 0, 0);
            accV[ct] = __builtin_amdgcn_mfma_f32_16x16x32_bf16(af1, bfV[ct][1], accV[ct], 0, 0, 0);
        }
        accS = __builtin_amdgcn_mfma_f32_16x16x32_bf16(af0, bu0, accS, 0, 0, 0);
        accS = __builtin_amdgcn_mfma_f32_16x16x32_bf16(af1, bu1, accS, 0, 0, 0);
        __builtin_amdgcn_s_setprio(0);

        // scores -> per-wave LDS patch (same-wave write/read; program order holds)
        if (ncol < Hh) {
            #pragma unroll
            for (int r = 0; r < 4; ++r)
                sS[w][q8 * 4 + r][ncol] = (maskv != 0.f) ? accS[r] : -1e30f;
        }
        __builtin_amdgcn_wave_barrier();

        #pragma unroll
        for (int r = 0; r < 4; ++r) {
            floatx4 sc = *(const floatx4*)&sS[w][q8 * 4 + r][0];
            // scores in log2 domain (log2e folded into u at prep): one v_exp_f32 each
            float e0 = __builtin_amdgcn_exp2f(sc[0]), e1 = __builtin_amdgcn_exp2f(sc[1]);
            float e2 = __builtin_amdgcn_exp2f(sc[2]), e3 = __builtin_amdgcn_exp2f(sc[3]);
            float inv = __builtin_amdgcn_rcpf((e0 + e1) + (e2 + e3));   // v_rcp_f32, ~1ulp
            float a0 = e0 * inv, a1 = e1 * inv, a2 = e2 * inv, a3 = e3 * inv;
            asumH += (ncol & 2) ? ((ncol & 1) ? a3 : a2) : ((ncol & 1) ? a1 : a0);
            float p;
            p = a0 * accV[0][r]; vs[0] += p; vm[0] = fmaxf(vm[0], p);
            p = a0 * accV[1][r]; vs[1] += p; vm[1] = fmaxf(vm[1], p);
            p = a1 * accV[2][r]; vs[2] += p; vm[2] = fmaxf(vm[2], p);
            p = a1 * accV[3][r]; vs[3] += p; vm[3] = fmaxf(vm[3], p);
            p = a2 * accV[4][r]; vs[4] += p; vm[4] = fmaxf(vm[4], p);
            p = a2 * accV[5][r]; vs[5] += p; vm[5] = fmaxf(vm[5], p);
            p = a3 * accV[6][r]; vs[6] += p; vm[6] = fmaxf(vm[6], p);
            p = a3 * accV[7][r]; vs[7] += p; vm[7] = fmaxf(vm[7], p);
        }
        __builtin_amdgcn_wave_barrier();   // sS reused next tile
    }
    #undef STAGE

    // q8-group reduction (once per wave)
    #pragma unroll
    for (int ct = 0; ct < 8; ++ct) {
        vs[ct] += __shfl_xor(vs[ct], 16, 64);
        vs[ct] += __shfl_xor(vs[ct], 32, 64);
        vm[ct] = fmaxf(vm[ct], __shfl_xor(vm[ct], 16, 64));
        vm[ct] = fmaxf(vm[ct], __shfl_xor(vm[ct], 32, 64));
    }
    asumH += __shfl_xor(asumH, 16, 64);
    asumH += __shfl_xor(asumH, 32, 64);

    // ---- epilogue in the dead sStage area ----
    // wave w region = its OWN staging area [w*2048, +2048):
    //   vs at [+0,+128), vm at [+128,+256), asum at [+256,+4).
    // Block scratch (post-sync only): sAsum at [512,516), sM at [768,1032),
    // sAcc at [1100,1612) — all inside wave 0's dead space, no overlap with
    // any live per-wave [base, base+260) region.
    float* SB = &sStage[0][0][0][0][0];
    if (lane < 16) {
        #pragma unroll
        for (int ct = 0; ct < 8; ++ct) {
            SB[w * 2048 + ct * 16 + lane]       = vs[ct];
            SB[w * 2048 + 128 + ct * 16 + lane] = vm[ct];
        }
    }
    if (lane < Hh) SB[w * 2048 + 256 + lane] = asumH;
    __syncthreads();
    if (tid < Hh) {
        float s = 1e-8f;
        #pragma unroll
        for (int ww = 0; ww < 8; ++ww) s += SB[ww * 2048 + 256 + tid];
        SB[512 + tid] = s;
    }
    __syncthreads();
    if (tid < OUTc) {
        float vsum = 0.f, vmax = -3.402823466e38f;
        #pragma unroll
        for (int ww = 0; ww < 8; ++ww) {
            vsum += SB[ww * 2048 + tid];
            vmax  = fmaxf(vmax, SB[ww * 2048 + 128 + tid]);
        }
        const int h = tid >> 5, d = tid & 31;
        SB[768 + h * 65 + d]      = vsum / SB[512 + h];
        SB[768 + h * 65 + 33 + d] = vmax;
        if (tid < Hh) SB[768 + tid * 65 + 32] = SB[512 + tid];
    }
    __syncthreads();
    // fused W_R GEMV on W_RT: 4 j-parts of 65 across 512 threads
    {
        const int c = tid & 127, part = tid >> 7;   // part 0..3
        const int j0 = part * 65;
        const float* sM = SB + 768;
        float a0 = 0.f, a1 = 0.f, a2 = 0.f, a3 = 0.f;
        #pragma unroll 4
        for (int j = j0; j < j0 + 64; j += 4) {
            a0 = fmaf(sM[j],     W_RT[(j)     * OUTc + c], a0);
            a1 = fmaf(sM[j + 1], W_RT[(j + 1) * OUTc + c], a1);
            a2 = fmaf(sM[j + 2], W_RT[(j + 2) * OUTc + c], a2);
            a3 = fmaf(sM[j + 3], W_RT[(j + 3) * OUTc + c], a3);
        }
        a0 = fmaf(sM[j0 + 64], W_RT[(j0 + 64) * OUTc + c], a0);
        SB[1100 + part * 128 + c] = (a0 + a1) + (a2 + a3);
    }
    __syncthreads();
    if (tid < OUTc)
        out[(size_t)bn * OUTc + tid] =
            (SB[1100 + tid] + SB[1100 + 128 + tid]) +
            (SB[1100 + 256 + tid] + SB[1100 + 384 + tid]);
}

extern "C" void kernel_launch(void* const* d_in, const int* in_sizes, int n_in,
                              void* d_out, int out_size, void* d_ws, size_t ws_size,
                              hipStream_t stream) {
    const float* h_x = (const float*)d_in[0];
    const float* h_e = (const float*)d_in[1];
    const float* h_m = (const float*)d_in[2];
    const float* W_Q = (const float*)d_in[3];
    const float* W_K = (const float*)d_in[4];
    const float* W_V = (const float*)d_in[5];
    const float* W_R = (const float*)d_in[6];
    float* out = (float*)d_out;

    float* ws            = (float*)d_ws;
    float* W_RT          = ws + WS_WRT;
    unsigned short* wfV  = (unsigned short*)(ws + WS_FRAGV);
    unsigned short* ufr  = (unsigned short*)(ws + WS_UFRAG);

    eama_prep<<<dim3(198), dim3(256), 0, stream>>>(W_Q, W_V, W_R, h_x, W_K, wfV, W_RT, ufr);
    eama_full<<<dim3(Bb * Nn), dim3(512), 0, stream>>>(h_e, h_m, wfV, ufr, W_RT, out);
}